// Round 7
// baseline (510.981 us; speedup 1.0000x reference)
//
#include <hip/hip_runtime.h>
#include <math.h>

#define Bb 4
#define Tt 2048
#define Cc 1024
#define Hh 16
#define Dd 64
#define FFf 2048
#define Mrows (Bb*Tt)   // 8192

typedef _Float16 f16;
typedef _Float16 half8 __attribute__((ext_vector_type(8)));
typedef _Float16 half4 __attribute__((ext_vector_type(4)));
typedef _Float16 half2 __attribute__((ext_vector_type(2)));
typedef float floatx4 __attribute__((ext_vector_type(4)));
typedef float floatx16 __attribute__((ext_vector_type(16)));

#define MFMA16(a,b,c)    __builtin_amdgcn_mfma_f32_16x16x32_f16(a,b,c,0,0,0)
#define MFMA16K16(a,b,c) __builtin_amdgcn_mfma_f32_16x16x16f16(a,b,c,0,0,0)
#define MFMA32(a,b,c)    __builtin_amdgcn_mfma_f32_32x32x16_f16(a,b,c,0,0,0)

// async global->LDS, 16B per lane; LDS dest = wave-uniform base + lane*16
__device__ __forceinline__ void g2l16(const void* g, void* l) {
  __builtin_amdgcn_global_load_lds((__attribute__((address_space(1))) void*)(g),
                                   (__attribute__((address_space(3))) void*)(l),
                                   16, 0, 0);
}

// fast gelu: Abramowitz-Stegun 7.1.26 erf (|eps|<=1.5e-7, far below f16 output
// precision). ~12 VALU ops vs libm erff's ~35.
__device__ __forceinline__ float fast_gelu(float t) {
  const float z  = t * 0.70710678118654752f;
  const float az = fabsf(z);
  const float u  = __builtin_amdgcn_rcpf(1.0f + 0.3275911f * az);
  const float p  = u*(0.254829592f + u*(-0.284496736f + u*(1.421413741f +
                   u*(-1.453152027f + u*1.061405429f))));
  const float e  = 1.0f - p * __builtin_amdgcn_exp2f(-az*az*1.44269504089f);
  const float er = (z < 0.0f) ? -e : e;
  return 0.5f * t * (1.0f + er);
}

// ---- fused: weight transpose (blocks 0..8191) + LayerNorm1 (blocks 8192..16383)
// ---- + inv-perm scatter (block 16384) ----
__global__ __launch_bounds__(256) void wt_ln_kernel(
    const float* __restrict__ Wqkv, const float* __restrict__ Wproj,
    const float* __restrict__ Wff1, const float* __restrict__ Wff2,
    f16* __restrict__ WqkvT, f16* __restrict__ WprojT,
    f16* __restrict__ Wff1T, f16* __restrict__ Wff2T,
    const float* __restrict__ x, const float* __restrict__ gam,
    const float* __restrict__ bet, f16* __restrict__ lnout,
    const int* __restrict__ perm, int* __restrict__ inv) {
  const int tid = threadIdx.x;
  if (blockIdx.x >= 16384) {
    // inv[perm[t]] = t : key with perm value j lives at original row inv[j]
    #pragma unroll
    for (int i = tid; i < Tt; i += 256) inv[perm[i]] = i;
    return;
  }
  if (blockIdx.x < 8192) {
    __shared__ float tile[32][33];
    int idx = blockIdx.x;
    const float* W; f16* WT; int K, N, n0, k0;
    if (idx < 3072)      { W = Wqkv;  WT = WqkvT;  K = Cc;  N = 3*Cc; n0 = (idx % 96)*32; k0 = (idx / 96)*32; }
    else if (idx < 4096) { idx -= 3072; W = Wproj; WT = WprojT; K = Cc;  N = Cc;  n0 = (idx % 32)*32; k0 = (idx / 32)*32; }
    else if (idx < 6144) { idx -= 4096; W = Wff1;  WT = Wff1T;  K = Cc;  N = FFf; n0 = (idx % 64)*32; k0 = (idx / 64)*32; }
    else                 { idx -= 6144; W = Wff2;  WT = Wff2T;  K = FFf; N = Cc;  n0 = (idx % 32)*32; k0 = (idx / 32)*32; }
    const int tx = tid & 31, ty = tid >> 5;
    #pragma unroll
    for (int i = 0; i < 4; i++)
      tile[ty + 8*i][tx] = W[(size_t)(k0 + ty + 8*i) * N + n0 + tx];
    __syncthreads();
    #pragma unroll
    for (int i = 0; i < 4; i++)
      WT[(size_t)(n0 + ty + 8*i) * K + k0 + tx] = (f16)tile[tx][ty + 8*i];
  } else {
    const int row = blockIdx.x - 8192;
    const float4 v = ((const float4*)(x + (size_t)row * Cc))[tid];
    float s  = v.x + v.y + v.z + v.w;
    float ss = v.x*v.x + v.y*v.y + v.z*v.z + v.w*v.w;
    #pragma unroll
    for (int o = 32; o >= 1; o >>= 1) { s += __shfl_xor(s, o); ss += __shfl_xor(ss, o); }
    __shared__ float ps[4], pss[4];
    if ((tid & 63) == 0) { ps[tid >> 6] = s; pss[tid >> 6] = ss; }
    __syncthreads();
    s  = ps[0] + ps[1] + ps[2] + ps[3];
    ss = pss[0] + pss[1] + pss[2] + pss[3];
    const float mu   = s * (1.0f / Cc);
    const float rstd = rsqrtf(ss * (1.0f / Cc) - mu * mu + 1e-5f);
    const float4 g4 = ((const float4*)gam)[tid];
    const float4 b4 = ((const float4*)bet)[tid];
    half4 o;
    o[0] = (f16)((v.x - mu) * rstd * g4.x + b4.x);
    o[1] = (f16)((v.y - mu) * rstd * g4.y + b4.y);
    o[2] = (f16)((v.z - mu) * rstd * g4.z + b4.z);
    o[3] = (f16)((v.w - mu) * rstd * g4.w + b4.w);
    ((half4*)(lnout + (size_t)row * Cc))[tid] = o;
  }
}

// ---------------- LayerNorm: fp32 in -> f16 out ----------------
__global__ __launch_bounds__(256) void ln_kernel(const float* __restrict__ x,
                                                 const float* __restrict__ gam,
                                                 const float* __restrict__ bet,
                                                 f16* __restrict__ out) {
  const int row = blockIdx.x;
  const int tid = threadIdx.x;
  const float4 v = ((const float4*)(x + (size_t)row * Cc))[tid];
  float s  = v.x + v.y + v.z + v.w;
  float ss = v.x*v.x + v.y*v.y + v.z*v.z + v.w*v.w;
  #pragma unroll
  for (int o = 32; o >= 1; o >>= 1) { s += __shfl_xor(s, o); ss += __shfl_xor(ss, o); }
  __shared__ float ps[4], pss[4];
  if ((tid & 63) == 0) { ps[tid >> 6] = s; pss[tid >> 6] = ss; }
  __syncthreads();
  s  = ps[0] + ps[1] + ps[2] + ps[3];
  ss = pss[0] + pss[1] + pss[2] + pss[3];
  const float mu   = s * (1.0f / Cc);
  const float rstd = rsqrtf(ss * (1.0f / Cc) - mu * mu + 1e-5f);
  const float4 g4 = ((const float4*)gam)[tid];
  const float4 b4 = ((const float4*)bet)[tid];
  half4 o;
  o[0] = (f16)((v.x - mu) * rstd * g4.x + b4.x);
  o[1] = (f16)((v.y - mu) * rstd * g4.y + b4.y);
  o[2] = (f16)((v.z - mu) * rstd * g4.z + b4.z);
  o[3] = (f16)((v.w - mu) * rstd * g4.w + b4.w);
  ((half4*)(out + (size_t)row * Cc))[tid] = o;
}

// -------- shared epilogue helper (32x32 C layout: col=lane&31, row=(reg&3)+8*(reg>>2)+4*khalf) --------
template <int MODE>
__device__ __forceinline__ void gemm_epilogue_tile(
    const floatx16& a, int rowBase, int col, int khalf,
    const float* __restrict__ resid, const float* __restrict__ bias,
    float* __restrict__ outF, f16* __restrict__ outH,
    f16* __restrict__ outQ, f16* __restrict__ outK, f16* __restrict__ outV) {
  if (MODE == 0) {
    const int s = col >> 10;
    const int hh = (col >> 6) & 15;
    const int d = col & 63;
    #pragma unroll
    for (int g = 0; g < 4; g++) {
      const int row0 = rowBase + 4*khalf + 8*g;
      const int bI = row0 >> 11;
      const int t0 = row0 & 2047;
      if (s == 2) {
        const size_t addr = (((size_t)(bI*Hh + hh)) * Dd + d) * Tt +
                            (t0 & ~63) + ((t0 >> 2) & 3)*16 + ((t0 >> 4) & 3)*4;
        half4 o;
        #pragma unroll
        for (int r = 0; r < 4; r++) o[r] = (f16)a[g*4 + r];
        *(half4*)&outV[addr] = o;
      } else {
        f16* dst = (s == 0) ? outQ : outK;
        const float sc = (s == 0) ? 0.18033688f : 1.0f;  // (1/8)*log2(e) folded into q
        #pragma unroll
        for (int r = 0; r < 4; r++)
          dst[(((size_t)(bI*Hh + hh)) * Tt + t0 + r) * Dd + d] = (f16)(a[g*4 + r] * sc);
      }
    }
  } else {
    #pragma unroll
    for (int g = 0; g < 4; g++) {
      #pragma unroll
      for (int r = 0; r < 4; r++) {
        const int row = rowBase + 4*khalf + 8*g + r;
        const float vv = a[g*4 + r];
        if (MODE == 1) {
          const size_t ad = (size_t)row * Cc + col;
          outF[ad] = vv + resid[ad] + bias[col];
        } else if (MODE == 2) {
          outH[(size_t)row * FFf + col] = (f16)fast_gelu(vv + bias[col]);
        } else {
          const size_t ad = (size_t)row * Cc + col;
          outF[ad] = vv + bias[col] + resid[ad];
        }
      }
    }
  }
}

// ------------- GEMM 128x128: A direct-from-L2, B via LDS -------------
// R6 post-mortem: all GEMMs pinned at ~30% MfmaUtil by LDS read BW (64KB frag
// reads + 32KB DMA writes per block-K-step vs 128 CU-cycles of MFMA). Fix: the
// MFMA32 A-fragment (row=lane&31, k=khalf*8+kk*16) is a contiguous 16B slice of
// row-major A, so each lane loads it straight from global (L2-resident: bm-slab
// per XCD = 2MB). LDS now holds only B: traffic halved, As deleted (LDS 16KB),
// staging DMA halved. L2-blocked swizzle unchanged (R2: FETCH 183->50MB).
// MODE 0 + bn>=8: A rows gathered via inv[] -> per-lane index loads at start.
template <int MODE>
__global__ __launch_bounds__(256, 4) void gemm_kernel(
    const f16* __restrict__ A, const f16* __restrict__ Bt, const int Kdim,
    const float* __restrict__ resid, const float* __restrict__ bias,
    float* __restrict__ outF, f16* __restrict__ outH,
    f16* __restrict__ outQ, f16* __restrict__ outK, f16* __restrict__ outV,
    const int* __restrict__ inv) {
  __shared__ f16 Bs[128 * 64];
  const int tid = threadIdx.x;
  const int lane = tid & 63;
  const int w = tid >> 6;
  const int wr = w >> 1, wc = w & 1;

  const int fid = blockIdx.y * gridDim.x + blockIdx.x;
  const int xcd = fid & 7;
  const int s = fid >> 3;
  const int r = s & 63;
  const int bm = xcd * 8 + (r >> 3);
  const int bn = (s >> 6) * 8 + (r & 7);

  floatx16 acc[2][2] = {};

  const int khalf = lane >> 5;

  // per-lane A fragment base pointers (row for mi=0,1; k-offset khalf*8)
  const f16* aBase[2];
  #pragma unroll
  for (int mi = 0; mi < 2; mi++) {
    const int rr = bm*128 + wr*64 + mi*32 + (lane & 31);
    int phys;
    if (MODE == 0 && bn >= 8) {
      phys = (rr >> 11) * Tt + inv[rr & 2047];
    } else {
      phys = rr;
    }
    aBase[mi] = A + (size_t)phys * Kdim + khalf * 8;
  }

  // B staging (unchanged): XOR-swizzled source column, DMA to linear LDS
  const int srow = lane >> 3;
  const int scol = ((lane & 7) ^ srow) * 8;
  const size_t bBase = (size_t)(bn*128 + w*32 + srow) * Kdim + scol;

  const int n0 = wc*64 + (lane & 31);
  const int mx = (lane & 7);

  for (int ks = 0; ks < Kdim; ks += 64) {
    __syncthreads();
    #pragma unroll
    for (int c = 0; c < 4; c++)
      g2l16(Bt + bBase + (size_t)(c*8)*Kdim + ks, &Bs[(w*32 + c*8) * 64]);
    __syncthreads();
    #pragma unroll
    for (int kk = 0; kk < 4; kk++) {
      const int kg = kk*2 + khalf;
      half8 aF[2], bF[2];
      aF[0] = *(const half8*)(aBase[0] + ks + kk*16);
      aF[1] = *(const half8*)(aBase[1] + ks + kk*16);
      bF[0] = *(const half8*)&Bs[(n0     ) * 64 + ((kg ^ mx) * 8)];
      bF[1] = *(const half8*)&Bs[(n0 + 32) * 64 + ((kg ^ mx) * 8)];
      acc[0][0] = MFMA32(aF[0], bF[0], acc[0][0]);
      acc[0][1] = MFMA32(aF[0], bF[1], acc[0][1]);
      acc[1][0] = MFMA32(aF[1], bF[0], acc[1][0]);
      acc[1][1] = MFMA32(aF[1], bF[1], acc[1][1]);
    }
  }

  #pragma unroll
  for (int mi = 0; mi < 2; mi++)
    #pragma unroll
    for (int ni = 0; ni < 2; ni++)
      gemm_epilogue_tile<MODE>(acc[mi][ni], bm*128 + wr*64 + mi*32,
                               bn*128 + wc*64 + ni*32 + (lane & 31), khalf,
                               resid, bias, outF, outH, outQ, outK, outV);
}

// ---------------- flash attention: 8-wave blocks, 128-q tile, 64-key staging ----------------
// Keys/values perm-sorted -> causal mask in sorted key index j: masked iff j > qrow.
// Each block = 512 threads (8 waves x 16 q-rows) processing TWO q-tiles (y, 15-y):
// exactly 36 key-block iterations per block, uniform under any scheduling.
__global__ __launch_bounds__(512, 4) void attn_kernel(
    const f16* __restrict__ Q, const f16* __restrict__ Kg,
    const f16* __restrict__ Vtp, f16* __restrict__ Y) {
  __shared__ f16 Ks[64 * 64];
  __shared__ f16 Vs[64 * 64];

  const int tid = threadIdx.x;
  const int lane = tid & 63;
  const int w = tid >> 6;
  const int low = lane & 15;
  const int quad = lane >> 4;
  const int bh = blockIdx.x;
  const int y = blockIdx.y;
  const int b = bh >> 4, h = bh & 15;

  const half4 ones4 = {(f16)1.f, (f16)1.f, (f16)1.f, (f16)1.f};
  const int gd = ((lane & 7) ^ (lane >> 3)) * 8;
  const int krow = lane >> 3;

  for (int pi = 0; pi < 2; pi++) {
    const int tile = (pi == 0) ? y : 15 - y;
    const int q0 = tile * 128;

    half8 qF[2];
    {
      const size_t base = ((size_t)bh * Tt + q0 + w*16) * Dd;
      #pragma unroll
      for (int kc = 0; kc < 2; kc++)
        qF[kc] = *(const half8*)(Q + base + (size_t)low * Dd + kc*32 + quad*8);
    }

    floatx4 O[4] = {};
    floatx4 Ol = {};
    const int nkb = (q0 >> 6) + 2;

    for (int kt = 0; kt < nkb; kt++) {
      const int kbase = kt * 64;
      __syncthreads();
      {
        const size_t kgBase = ((size_t)bh * Tt + kbase) * Dd;
        const size_t vgBase = ((size_t)bh * Dd) * Tt + kbase;
        g2l16(Kg  + kgBase + (size_t)(w*8 + krow) * Dd + gd, &Ks[w * 512]);
        g2l16(Vtp + vgBase + (size_t)(w*8 + krow) * Tt + gd, &Vs[w * 512]);
      }
      __syncthreads();

      floatx4 S[4] = {};
      #pragma unroll
      for (int kc = 0; kc < 2; kc++) {
        #pragma unroll
        for (int ki = 0; ki < 4; ki++) {
          const int key = ki*16 + low;
          const half8 kf = *(const half8*)&Ks[key * 64 + (((kc*4 + quad) ^ (lane & 7)) * 8)];
          S[ki] = MFMA16(kf, qF[kc], S[ki]);
        }
      }

      half4 pF[4];
      const bool needmask = (kbase + 63 > q0 + w*16);  // wave-uniform
      if (needmask) {
        const int qrow = q0 + w*16 + low;
        #pragma unroll
        for (int ki = 0; ki < 4; ki++) {
          const floatx4 sv = S[ki];
          const int kj = kbase + ki*16 + quad*4;
          const float p0 = (kj + 0 > qrow) ? 0.f : __builtin_amdgcn_exp2f(sv[0]);
          const float p1 = (kj + 1 > qrow) ? 0.f : __builtin_amdgcn_exp2f(sv[1]);
          const float p2 = (kj + 2 > qrow) ? 0.f : __builtin_amdgcn_exp2f(sv[2]);
          const float p3 = (kj + 3 > qrow) ? 0.f : __builtin_amdgcn_exp2f(sv[3]);
          const half2 lo = __builtin_bit_cast(half2, __builtin_amdgcn_cvt_pkrtz(p0, p1));
          const half2 hi = __builtin_bit_cast(half2, __builtin_amdgcn_cvt_pkrtz(p2, p3));
          pF[ki] = __builtin_shufflevector(lo, hi, 0, 1, 2, 3);
        }
      } else {
        #pragma unroll
        for (int ki = 0; ki < 4; ki++) {
          const floatx4 sv = S[ki];
          const float p0 = __builtin_amdgcn_exp2f(sv[0]);
          const float p1 = __builtin_amdgcn_exp2f(sv[1]);
          const float p2 = __builtin_amdgcn_exp2f(sv[2]);
          const float p3 = __builtin_amdgcn_exp2f(sv[3]);
          const half2 lo = __builtin_bit_cast(half2, __builtin_amdgcn_cvt_pkrtz(p0, p1));
          const half2 hi = __builtin_bit_cast(half2, __builtin_amdgcn_cvt_pkrtz(p2, p3));
          pF[ki] = __builtin_shufflevector(lo, hi, 0, 1, 2, 3);
        }
      }

      #pragma unroll
      for (int ki2 = 0; ki2 < 2; ki2++) {
        Ol = MFMA16K16(ones4, pF[2*ki2 + 0], Ol);
        Ol = MFMA16K16(ones4, pF[2*ki2 + 1], Ol);
        #pragma unroll
        for (int ni = 0; ni < 4; ni++) {
          const int d = ni*16 + low;
          const half8 v8 = *(const half8*)&Vs[d * 64 + (((quad*2 + ki2) ^ (lane & 7)) * 8)];
          const half4 vfA = __builtin_shufflevector(v8, v8, 0, 1, 2, 3);
          const half4 vfB = __builtin_shufflevector(v8, v8, 4, 5, 6, 7);
          O[ni] = MFMA16K16(vfA, pF[2*ki2 + 0], O[ni]);
          O[ni] = MFMA16K16(vfB, pF[2*ki2 + 1], O[ni]);
        }
      }
    }

    {
      const float linv = 1.0f / Ol[0];
      const int trow = q0 + w*16 + low;
      #pragma unroll
      for (int ni = 0; ni < 4; ni++) {
        half4 o;
        #pragma unroll
        for (int rr = 0; rr < 4; rr++) o[rr] = (f16)(O[ni][rr] * linv);
        *(half4*)&Y[((size_t)(b * Tt + trow)) * Cc + h*64 + ni*16 + quad*4] = o;
      }
    }
  }
}

extern "C" void kernel_launch(void* const* d_in, const int* in_sizes, int n_in,
                              void* d_out, int out_size, void* d_ws, size_t ws_size,
                              hipStream_t stream) {
  const float* x     = (const float*)d_in[0];
  const int*   perm  = (const int*)d_in[1];
  const float* Wqkv  = (const float*)d_in[2];
  const float* Wproj = (const float*)d_in[3];
  const float* bproj = (const float*)d_in[4];
  const float* ln1g  = (const float*)d_in[5];
  const float* ln1b  = (const float*)d_in[6];
  const float* ln2g  = (const float*)d_in[7];
  const float* ln2b  = (const float*)d_in[8];
  const float* Wff1  = (const float*)d_in[9];
  const float* bff1  = (const float*)d_in[10];
  const float* Wff2  = (const float*)d_in[11];
  const float* bff2  = (const float*)d_in[12];
  float* out = (float*)d_out;

  char* ws = (char*)d_ws;
  size_t off = 0;
  auto alloc = [&](size_t bytes) -> void* {
    void* p = ws + off;
    off += (bytes + 255) & ~(size_t)255;
    return p;
  };
  f16*   h1     = (f16*)alloc((size_t)Mrows * Cc * 2);
  f16*   qb     = (f16*)alloc((size_t)Mrows * Cc * 2);
  f16*   kb     = (f16*)alloc((size_t)Mrows * Cc * 2);
  f16*   vtp    = (f16*)alloc((size_t)Mrows * Cc * 2);
  f16*   yb     = (f16*)alloc((size_t)Mrows * Cc * 2);
  float* xa     = (float*)alloc((size_t)Mrows * Cc * 4);
  f16*   h2     = (f16*)alloc((size_t)Mrows * Cc * 2);
  f16*   gb     = (f16*)alloc((size_t)Mrows * FFf * 2);
  f16*   WqkvT  = (f16*)alloc((size_t)3 * Cc * Cc * 2);
  f16*   WprojT = (f16*)alloc((size_t)Cc * Cc * 2);
  f16*   Wff1T  = (f16*)alloc((size_t)FFf * Cc * 2);
  f16*   Wff2T  = (f16*)alloc((size_t)Cc * FFf * 2);
  int*   inv    = (int*)alloc((size_t)Tt * 4);

  wt_ln_kernel<<<16385, 256, 0, stream>>>(Wqkv, Wproj, Wff1, Wff2,
                                          WqkvT, WprojT, Wff1T, Wff2T,
                                          x, ln1g, ln1b, h1, perm, inv);

  gemm_kernel<0><<<dim3(3*Cc/128, Mrows/128), 256, 0, stream>>>(
      h1, WqkvT, Cc, nullptr, nullptr, nullptr, nullptr, qb, kb, vtp, inv);

  attn_kernel<<<dim3(Bb*Hh, Tt/256), 512, 0, stream>>>(qb, kb, vtp, yb);

  gemm_kernel<1><<<dim3(Cc/128, Mrows/128), 256, 0, stream>>>(
      yb, WprojT, Cc, x, bproj, xa, nullptr, nullptr, nullptr, nullptr, nullptr);

  ln_kernel<<<Mrows, 256, 0, stream>>>(xa, ln2g, ln2b, h2);

  gemm_kernel<2><<<dim3(FFf/128, Mrows/128), 256, 0, stream>>>(
      h2, Wff1T, Cc, nullptr, bff1, nullptr, gb, nullptr, nullptr, nullptr, nullptr);

  gemm_kernel<3><<<dim3(Cc/128, Mrows/128), 256, 0, stream>>>(
      gb, Wff2T, FFf, xa, bff2, out, nullptr, nullptr, nullptr, nullptr, nullptr);
}

// Round 8
// 388.294 us; speedup vs baseline: 1.3160x; 1.3160x over previous
//
#include <hip/hip_runtime.h>
#include <math.h>

#define Bb 4
#define Tt 2048
#define Cc 1024
#define Hh 16
#define Dd 64
#define FFf 2048
#define Mrows (Bb*Tt)   // 8192

typedef _Float16 f16;
typedef _Float16 half8 __attribute__((ext_vector_type(8)));
typedef _Float16 half4 __attribute__((ext_vector_type(4)));
typedef _Float16 half2 __attribute__((ext_vector_type(2)));
typedef float floatx4 __attribute__((ext_vector_type(4)));
typedef float floatx16 __attribute__((ext_vector_type(16)));

#define MFMA16(a,b,c)    __builtin_amdgcn_mfma_f32_16x16x32_f16(a,b,c,0,0,0)
#define MFMA16K16(a,b,c) __builtin_amdgcn_mfma_f32_16x16x16f16(a,b,c,0,0,0)
#define MFMA32(a,b,c)    __builtin_amdgcn_mfma_f32_32x32x16_f16(a,b,c,0,0,0)

// async global->LDS, 16B per lane; LDS dest = wave-uniform base + lane*16
__device__ __forceinline__ void g2l16(const void* g, void* l) {
  __builtin_amdgcn_global_load_lds((__attribute__((address_space(1))) void*)(g),
                                   (__attribute__((address_space(3))) void*)(l),
                                   16, 0, 0);
}

// fast gelu: Abramowitz-Stegun 7.1.26 erf (|eps|<=1.5e-7, far below f16 output
// precision). ~12 VALU ops vs libm erff's ~35.
__device__ __forceinline__ float fast_gelu(float t) {
  const float z  = t * 0.70710678118654752f;
  const float az = fabsf(z);
  const float u  = __builtin_amdgcn_rcpf(1.0f + 0.3275911f * az);
  const float p  = u*(0.254829592f + u*(-0.284496736f + u*(1.421413741f +
                   u*(-1.453152027f + u*1.061405429f))));
  const float e  = 1.0f - p * __builtin_amdgcn_exp2f(-az*az*1.44269504089f);
  const float er = (z < 0.0f) ? -e : e;
  return 0.5f * t * (1.0f + er);
}

// ---- fused: weight transpose (blocks 0..8191) + LayerNorm1 (blocks 8192..16383)
// ---- + inv-perm scatter (block 16384) ----
__global__ __launch_bounds__(256) void wt_ln_kernel(
    const float* __restrict__ Wqkv, const float* __restrict__ Wproj,
    const float* __restrict__ Wff1, const float* __restrict__ Wff2,
    f16* __restrict__ WqkvT, f16* __restrict__ WprojT,
    f16* __restrict__ Wff1T, f16* __restrict__ Wff2T,
    const float* __restrict__ x, const float* __restrict__ gam,
    const float* __restrict__ bet, f16* __restrict__ lnout,
    const int* __restrict__ perm, int* __restrict__ inv) {
  const int tid = threadIdx.x;
  if (blockIdx.x >= 16384) {
    // inv[perm[t]] = t : key with perm value j lives at original row inv[j]
    #pragma unroll
    for (int i = tid; i < Tt; i += 256) inv[perm[i]] = i;
    return;
  }
  if (blockIdx.x < 8192) {
    __shared__ float tile[32][33];
    int idx = blockIdx.x;
    const float* W; f16* WT; int K, N, n0, k0;
    if (idx < 3072)      { W = Wqkv;  WT = WqkvT;  K = Cc;  N = 3*Cc; n0 = (idx % 96)*32; k0 = (idx / 96)*32; }
    else if (idx < 4096) { idx -= 3072; W = Wproj; WT = WprojT; K = Cc;  N = Cc;  n0 = (idx % 32)*32; k0 = (idx / 32)*32; }
    else if (idx < 6144) { idx -= 4096; W = Wff1;  WT = Wff1T;  K = Cc;  N = FFf; n0 = (idx % 64)*32; k0 = (idx / 64)*32; }
    else                 { idx -= 6144; W = Wff2;  WT = Wff2T;  K = FFf; N = Cc;  n0 = (idx % 32)*32; k0 = (idx / 32)*32; }
    const int tx = tid & 31, ty = tid >> 5;
    #pragma unroll
    for (int i = 0; i < 4; i++)
      tile[ty + 8*i][tx] = W[(size_t)(k0 + ty + 8*i) * N + n0 + tx];
    __syncthreads();
    #pragma unroll
    for (int i = 0; i < 4; i++)
      WT[(size_t)(n0 + ty + 8*i) * K + k0 + tx] = (f16)tile[tx][ty + 8*i];
  } else {
    const int row = blockIdx.x - 8192;
    const float4 v = ((const float4*)(x + (size_t)row * Cc))[tid];
    float s  = v.x + v.y + v.z + v.w;
    float ss = v.x*v.x + v.y*v.y + v.z*v.z + v.w*v.w;
    #pragma unroll
    for (int o = 32; o >= 1; o >>= 1) { s += __shfl_xor(s, o); ss += __shfl_xor(ss, o); }
    __shared__ float ps[4], pss[4];
    if ((tid & 63) == 0) { ps[tid >> 6] = s; pss[tid >> 6] = ss; }
    __syncthreads();
    s  = ps[0] + ps[1] + ps[2] + ps[3];
    ss = pss[0] + pss[1] + pss[2] + pss[3];
    const float mu   = s * (1.0f / Cc);
    const float rstd = rsqrtf(ss * (1.0f / Cc) - mu * mu + 1e-5f);
    const float4 g4 = ((const float4*)gam)[tid];
    const float4 b4 = ((const float4*)bet)[tid];
    half4 o;
    o[0] = (f16)((v.x - mu) * rstd * g4.x + b4.x);
    o[1] = (f16)((v.y - mu) * rstd * g4.y + b4.y);
    o[2] = (f16)((v.z - mu) * rstd * g4.z + b4.z);
    o[3] = (f16)((v.w - mu) * rstd * g4.w + b4.w);
    ((half4*)(lnout + (size_t)row * Cc))[tid] = o;
  }
}

// ---------------- LayerNorm: fp32 in -> f16 out ----------------
__global__ __launch_bounds__(256) void ln_kernel(const float* __restrict__ x,
                                                 const float* __restrict__ gam,
                                                 const float* __restrict__ bet,
                                                 f16* __restrict__ out) {
  const int row = blockIdx.x;
  const int tid = threadIdx.x;
  const float4 v = ((const float4*)(x + (size_t)row * Cc))[tid];
  float s  = v.x + v.y + v.z + v.w;
  float ss = v.x*v.x + v.y*v.y + v.z*v.z + v.w*v.w;
  #pragma unroll
  for (int o = 32; o >= 1; o >>= 1) { s += __shfl_xor(s, o); ss += __shfl_xor(ss, o); }
  __shared__ float ps[4], pss[4];
  if ((tid & 63) == 0) { ps[tid >> 6] = s; pss[tid >> 6] = ss; }
  __syncthreads();
  s  = ps[0] + ps[1] + ps[2] + ps[3];
  ss = pss[0] + pss[1] + pss[2] + pss[3];
  const float mu   = s * (1.0f / Cc);
  const float rstd = rsqrtf(ss * (1.0f / Cc) - mu * mu + 1e-5f);
  const float4 g4 = ((const float4*)gam)[tid];
  const float4 b4 = ((const float4*)bet)[tid];
  half4 o;
  o[0] = (f16)((v.x - mu) * rstd * g4.x + b4.x);
  o[1] = (f16)((v.y - mu) * rstd * g4.y + b4.y);
  o[2] = (f16)((v.z - mu) * rstd * g4.z + b4.z);
  o[3] = (f16)((v.w - mu) * rstd * g4.w + b4.w);
  ((half4*)(out + (size_t)row * Cc))[tid] = o;
}

// -------- shared epilogue helper (32x32 C layout: col=lane&31, row=(reg&3)+8*(reg>>2)+4*khalf) --------
template <int MODE>
__device__ __forceinline__ void gemm_epilogue_tile(
    const floatx16& a, int rowBase, int col, int khalf,
    const float* __restrict__ resid, const float* __restrict__ bias,
    float* __restrict__ outF, f16* __restrict__ outH,
    f16* __restrict__ outQ, f16* __restrict__ outK, f16* __restrict__ outV) {
  if (MODE == 0) {
    const int s = col >> 10;
    const int hh = (col >> 6) & 15;
    const int d = col & 63;
    #pragma unroll
    for (int g = 0; g < 4; g++) {
      const int row0 = rowBase + 4*khalf + 8*g;
      const int bI = row0 >> 11;
      const int t0 = row0 & 2047;
      if (s == 2) {
        const size_t addr = (((size_t)(bI*Hh + hh)) * Dd + d) * Tt +
                            (t0 & ~63) + ((t0 >> 2) & 3)*16 + ((t0 >> 4) & 3)*4;
        half4 o;
        #pragma unroll
        for (int r = 0; r < 4; r++) o[r] = (f16)a[g*4 + r];
        *(half4*)&outV[addr] = o;
      } else {
        f16* dst = (s == 0) ? outQ : outK;
        const float sc = (s == 0) ? 0.18033688f : 1.0f;  // (1/8)*log2(e) folded into q
        #pragma unroll
        for (int r = 0; r < 4; r++)
          dst[(((size_t)(bI*Hh + hh)) * Tt + t0 + r) * Dd + d] = (f16)(a[g*4 + r] * sc);
      }
    }
  } else {
    #pragma unroll
    for (int g = 0; g < 4; g++) {
      #pragma unroll
      for (int r = 0; r < 4; r++) {
        const int row = rowBase + 4*khalf + 8*g + r;
        const float vv = a[g*4 + r];
        if (MODE == 1) {
          const size_t ad = (size_t)row * Cc + col;
          outF[ad] = vv + resid[ad] + bias[col];
        } else if (MODE == 2) {
          outH[(size_t)row * FFf + col] = (f16)fast_gelu(vv + bias[col]);
        } else {
          const size_t ad = (size_t)row * Cc + col;
          outF[ad] = vv + bias[col] + resid[ad];
        }
      }
    }
  }
}

// ------------- GEMM 128x128: 32x32x16 MFMA, BK=64, swizzled staging -------------
// R6-proven version restored verbatim (R7's A-direct-from-L2 regressed to 15%
// MfmaUtil: scattered per-lane 16B L2 requests, latency-exposed in the kk loop).
// This structure's ~700 TF is its ceiling: the 4-way LDS read aliasing is
// inherent (128B rows have only 8 16B slots; 32 lanes/same-k can't spread wider).
// L2-blocked swizzle: each XCD (fid&7) owns a contiguous 8-bm slab; bn inner in
// groups of 8 (R2: FETCH 183MB->50MB). MODE 0 + bn>=8: A rows gathered via inv[].
template <int MODE>
__global__ __launch_bounds__(256, 4) void gemm_kernel(
    const f16* __restrict__ A, const f16* __restrict__ Bt, const int Kdim,
    const float* __restrict__ resid, const float* __restrict__ bias,
    float* __restrict__ outF, f16* __restrict__ outH,
    f16* __restrict__ outQ, f16* __restrict__ outK, f16* __restrict__ outV,
    const int* __restrict__ inv) {
  __shared__ f16 As[128 * 64];
  __shared__ f16 Bs[128 * 64];
  const int tid = threadIdx.x;
  const int lane = tid & 63;
  const int w = tid >> 6;
  const int wr = w >> 1, wc = w & 1;

  const int fid = blockIdx.y * gridDim.x + blockIdx.x;
  const int xcd = fid & 7;
  const int s = fid >> 3;
  const int r = s & 63;
  const int bm = xcd * 8 + (r >> 3);
  const int bn = (s >> 6) * 8 + (r & 7);

  floatx16 acc[2][2] = {};

  const int srow = lane >> 3;
  const int scol = ((lane & 7) ^ srow) * 8;
  size_t aRow[4];
  {
    const int r0 = bm*128 + w*32 + srow;
    if (MODE == 0 && bn >= 8) {
      const int bI = r0 >> 11;
      const int t0 = r0 & 2047;
      #pragma unroll
      for (int c = 0; c < 4; c++)
        aRow[c] = (size_t)(bI*Tt + inv[t0 + c*8]) * Kdim + scol;
    } else {
      #pragma unroll
      for (int c = 0; c < 4; c++)
        aRow[c] = (size_t)(r0 + c*8) * Kdim + scol;
    }
  }
  const size_t bBase = (size_t)(bn*128 + w*32 + srow) * Kdim + scol;

  const int m0 = wr*64 + (lane & 31);
  const int n0 = wc*64 + (lane & 31);
  const int khalf = lane >> 5;
  const int mx = (lane & 7);

  for (int ks = 0; ks < Kdim; ks += 64) {
    __syncthreads();
    #pragma unroll
    for (int c = 0; c < 4; c++) {
      g2l16(A  + aRow[c] + ks, &As[(w*32 + c*8) * 64]);
      g2l16(Bt + bBase + (size_t)(c*8)*Kdim + ks, &Bs[(w*32 + c*8) * 64]);
    }
    __syncthreads();
    #pragma unroll
    for (int kk = 0; kk < 4; kk++) {
      const int kg = kk*2 + khalf;
      half8 aF[2], bF[2];
      aF[0] = *(const half8*)&As[(m0     ) * 64 + ((kg ^ mx) * 8)];
      aF[1] = *(const half8*)&As[(m0 + 32) * 64 + ((kg ^ mx) * 8)];
      bF[0] = *(const half8*)&Bs[(n0     ) * 64 + ((kg ^ mx) * 8)];
      bF[1] = *(const half8*)&Bs[(n0 + 32) * 64 + ((kg ^ mx) * 8)];
      acc[0][0] = MFMA32(aF[0], bF[0], acc[0][0]);
      acc[0][1] = MFMA32(aF[0], bF[1], acc[0][1]);
      acc[1][0] = MFMA32(aF[1], bF[0], acc[1][0]);
      acc[1][1] = MFMA32(aF[1], bF[1], acc[1][1]);
    }
  }

  #pragma unroll
  for (int mi = 0; mi < 2; mi++)
    #pragma unroll
    for (int ni = 0; ni < 2; ni++)
      gemm_epilogue_tile<MODE>(acc[mi][ni], bm*128 + wr*64 + mi*32,
                               bn*128 + wc*64 + ni*32 + (lane & 31), khalf,
                               resid, bias, outF, outH, outQ, outK, outV);
}

// ---------------- flash attention: 8-wave blocks, double-buffered K/V staging ----------------
// Keys/values perm-sorted -> causal mask in sorted key index j: masked iff j > qrow.
// Each block = 512 threads (8 waves x 16 q-rows) processing TWO q-tiles (y, 15-y):
// exactly 36 key-block iterations per block, uniform under any scheduling.
// R8: issue-early double-buffer (T3-minimum): stage kt+1 into alternate 16KB buffer
// BEFORE computing kt; single __syncthreads per iteration (its implicit vmcnt drain
// lands the prefetch, which had the whole QK+softmax+PV phase in flight). Safety:
// buf[cur^1] was last read in iter kt-1; kt-1's trailing barrier orders those reads
// before this iteration's staging overwrites it.
__global__ __launch_bounds__(512, 4) void attn_kernel(
    const f16* __restrict__ Q, const f16* __restrict__ Kg,
    const f16* __restrict__ Vtp, f16* __restrict__ Y) {
  __shared__ f16 Ks[2][64 * 64];
  __shared__ f16 Vs[2][64 * 64];

  const int tid = threadIdx.x;
  const int lane = tid & 63;
  const int w = tid >> 6;
  const int low = lane & 15;
  const int quad = lane >> 4;
  const int bh = blockIdx.x;
  const int y = blockIdx.y;
  const int b = bh >> 4, h = bh & 15;

  const half4 ones4 = {(f16)1.f, (f16)1.f, (f16)1.f, (f16)1.f};
  const int gd = ((lane & 7) ^ (lane >> 3)) * 8;
  const int krow = lane >> 3;
  const size_t kgB = (size_t)bh * Tt * Dd + (size_t)(w*8 + krow) * Dd + gd;
  const size_t vgB = (size_t)bh * Dd * Tt + (size_t)(w*8 + krow) * Tt + gd;

  for (int pi = 0; pi < 2; pi++) {
    const int tile = (pi == 0) ? y : 15 - y;
    const int q0 = tile * 128;

    half8 qF[2];
    {
      const size_t base = ((size_t)bh * Tt + q0 + w*16) * Dd;
      #pragma unroll
      for (int kc = 0; kc < 2; kc++)
        qF[kc] = *(const half8*)(Q + base + (size_t)low * Dd + kc*32 + quad*8);
    }

    floatx4 O[4] = {};
    floatx4 Ol = {};
    const int nkb = (q0 >> 6) + 2;

    // prologue: stage kt=0 into buffer 0 (prev pi's trailing barrier guards reuse)
    g2l16(Kg  + kgB, &Ks[0][w * 512]);
    g2l16(Vtp + vgB, &Vs[0][w * 512]);
    __syncthreads();

    for (int kt = 0; kt < nkb; kt++) {
      const int cur = kt & 1;
      const int kbase = kt * 64;
      if (kt + 1 < nkb) {
        g2l16(Kg  + kgB + (size_t)(kbase + 64) * Dd, &Ks[cur ^ 1][w * 512]);
        g2l16(Vtp + vgB + (kbase + 64),              &Vs[cur ^ 1][w * 512]);
      }
      const f16* Kc = &Ks[cur][0];
      const f16* Vc = &Vs[cur][0];

      floatx4 S[4] = {};
      #pragma unroll
      for (int kc = 0; kc < 2; kc++) {
        #pragma unroll
        for (int ki = 0; ki < 4; ki++) {
          const int key = ki*16 + low;
          const half8 kf = *(const half8*)&Kc[key * 64 + (((kc*4 + quad) ^ (lane & 7)) * 8)];
          S[ki] = MFMA16(kf, qF[kc], S[ki]);
        }
      }

      half4 pF[4];
      const bool needmask = (kbase + 63 > q0 + w*16);  // wave-uniform
      if (needmask) {
        const int qrow = q0 + w*16 + low;
        #pragma unroll
        for (int ki = 0; ki < 4; ki++) {
          const floatx4 sv = S[ki];
          const int kj = kbase + ki*16 + quad*4;
          const float p0 = (kj + 0 > qrow) ? 0.f : __builtin_amdgcn_exp2f(sv[0]);
          const float p1 = (kj + 1 > qrow) ? 0.f : __builtin_amdgcn_exp2f(sv[1]);
          const float p2 = (kj + 2 > qrow) ? 0.f : __builtin_amdgcn_exp2f(sv[2]);
          const float p3 = (kj + 3 > qrow) ? 0.f : __builtin_amdgcn_exp2f(sv[3]);
          const half2 lo = __builtin_bit_cast(half2, __builtin_amdgcn_cvt_pkrtz(p0, p1));
          const half2 hi = __builtin_bit_cast(half2, __builtin_amdgcn_cvt_pkrtz(p2, p3));
          pF[ki] = __builtin_shufflevector(lo, hi, 0, 1, 2, 3);
        }
      } else {
        #pragma unroll
        for (int ki = 0; ki < 4; ki++) {
          const floatx4 sv = S[ki];
          const float p0 = __builtin_amdgcn_exp2f(sv[0]);
          const float p1 = __builtin_amdgcn_exp2f(sv[1]);
          const float p2 = __builtin_amdgcn_exp2f(sv[2]);
          const float p3 = __builtin_amdgcn_exp2f(sv[3]);
          const half2 lo = __builtin_bit_cast(half2, __builtin_amdgcn_cvt_pkrtz(p0, p1));
          const half2 hi = __builtin_bit_cast(half2, __builtin_amdgcn_cvt_pkrtz(p2, p3));
          pF[ki] = __builtin_shufflevector(lo, hi, 0, 1, 2, 3);
        }
      }

      #pragma unroll
      for (int ki2 = 0; ki2 < 2; ki2++) {
        Ol = MFMA16K16(ones4, pF[2*ki2 + 0], Ol);
        Ol = MFMA16K16(ones4, pF[2*ki2 + 1], Ol);
        #pragma unroll
        for (int ni = 0; ni < 4; ni++) {
          const int d = ni*16 + low;
          const half8 v8 = *(const half8*)&Vc[d * 64 + (((quad*2 + ki2) ^ (lane & 7)) * 8)];
          const half4 vfA = __builtin_shufflevector(v8, v8, 0, 1, 2, 3);
          const half4 vfB = __builtin_shufflevector(v8, v8, 4, 5, 6, 7);
          O[ni] = MFMA16K16(vfA, pF[2*ki2 + 0], O[ni]);
          O[ni] = MFMA16K16(vfB, pF[2*ki2 + 1], O[ni]);
        }
      }
      __syncthreads();
    }

    {
      const float linv = 1.0f / Ol[0];
      const int trow = q0 + w*16 + low;
      #pragma unroll
      for (int ni = 0; ni < 4; ni++) {
        half4 o;
        #pragma unroll
        for (int rr = 0; rr < 4; rr++) o[rr] = (f16)(O[ni][rr] * linv);
        *(half4*)&Y[((size_t)(b * Tt + trow)) * Cc + h*64 + ni*16 + quad*4] = o;
      }
    }
  }
}

extern "C" void kernel_launch(void* const* d_in, const int* in_sizes, int n_in,
                              void* d_out, int out_size, void* d_ws, size_t ws_size,
                              hipStream_t stream) {
  const float* x     = (const float*)d_in[0];
  const int*   perm  = (const int*)d_in[1];
  const float* Wqkv  = (const float*)d_in[2];
  const float* Wproj = (const float*)d_in[3];
  const float* bproj = (const float*)d_in[4];
  const float* ln1g  = (const float*)d_in[5];
  const float* ln1b  = (const float*)d_in[6];
  const float* ln2g  = (const float*)d_in[7];
  const float* ln2b  = (const float*)d_in[8];
  const float* Wff1  = (const float*)d_in[9];
  const float* bff1  = (const float*)d_in[10];
  const float* Wff2  = (const float*)d_in[11];
  const float* bff2  = (const float*)d_in[12];
  float* out = (float*)d_out;

  char* ws = (char*)d_ws;
  size_t off = 0;
  auto alloc = [&](size_t bytes) -> void* {
    void* p = ws + off;
    off += (bytes + 255) & ~(size_t)255;
    return p;
  };
  f16*   h1     = (f16*)alloc((size_t)Mrows * Cc * 2);
  f16*   qb     = (f16*)alloc((size_t)Mrows * Cc * 2);
  f16*   kb     = (f16*)alloc((size_t)Mrows * Cc * 2);
  f16*   vtp    = (f16*)alloc((size_t)Mrows * Cc * 2);
  f16*   yb     = (f16*)alloc((size_t)Mrows * Cc * 2);
  float* xa     = (float*)alloc((size_t)Mrows * Cc * 4);
  f16*   h2     = (f16*)alloc((size_t)Mrows * Cc * 2);
  f16*   gb     = (f16*)alloc((size_t)Mrows * FFf * 2);
  f16*   WqkvT  = (f16*)alloc((size_t)3 * Cc * Cc * 2);
  f16*   WprojT = (f16*)alloc((size_t)Cc * Cc * 2);
  f16*   Wff1T  = (f16*)alloc((size_t)FFf * Cc * 2);
  f16*   Wff2T  = (f16*)alloc((size_t)Cc * FFf * 2);
  int*   inv    = (int*)alloc((size_t)Tt * 4);

  wt_ln_kernel<<<16385, 256, 0, stream>>>(Wqkv, Wproj, Wff1, Wff2,
                                          WqkvT, WprojT, Wff1T, Wff2T,
                                          x, ln1g, ln1b, h1, perm, inv);

  gemm_kernel<0><<<dim3(3*Cc/128, Mrows/128), 256, 0, stream>>>(
      h1, WqkvT, Cc, nullptr, nullptr, nullptr, nullptr, qb, kb, vtp, inv);

  attn_kernel<<<dim3(Bb*Hh, Tt/256), 512, 0, stream>>>(qb, kb, vtp, yb);

  gemm_kernel<1><<<dim3(Cc/128, Mrows/128), 256, 0, stream>>>(
      yb, WprojT, Cc, x, bproj, xa, nullptr, nullptr, nullptr, nullptr, nullptr);

  ln_kernel<<<Mrows, 256, 0, stream>>>(xa, ln2g, ln2b, h2);

  gemm_kernel<2><<<dim3(FFf/128, Mrows/128), 256, 0, stream>>>(
      h2, Wff1T, Cc, nullptr, bff1, nullptr, gb, nullptr, nullptr, nullptr, nullptr);

  gemm_kernel<3><<<dim3(Cc/128, Mrows/128), 256, 0, stream>>>(
      gb, Wff2T, FFf, xa, bff2, out, nullptr, nullptr, nullptr, nullptr, nullptr);
}

// Round 11
// 372.270 us; speedup vs baseline: 1.3726x; 1.0430x over previous
//
#include <hip/hip_runtime.h>
#include <math.h>

#define Bb 4
#define Tt 2048
#define Cc 1024
#define Hh 16
#define Dd 64
#define FFf 2048
#define Mrows (Bb*Tt)   // 8192

typedef _Float16 f16;
typedef _Float16 half8 __attribute__((ext_vector_type(8)));
typedef _Float16 half4 __attribute__((ext_vector_type(4)));
typedef _Float16 half2 __attribute__((ext_vector_type(2)));
typedef float floatx4 __attribute__((ext_vector_type(4)));
typedef float floatx16 __attribute__((ext_vector_type(16)));

#define MFMA16(a,b,c)    __builtin_amdgcn_mfma_f32_16x16x32_f16(a,b,c,0,0,0)
#define MFMA16K16(a,b,c) __builtin_amdgcn_mfma_f32_16x16x16f16(a,b,c,0,0,0)
#define MFMA32(a,b,c)    __builtin_amdgcn_mfma_f32_32x32x16_f16(a,b,c,0,0,0)

// async global->LDS, 16B per lane; LDS dest = wave-uniform base + lane*16
__device__ __forceinline__ void g2l16(const void* g, void* l) {
  __builtin_amdgcn_global_load_lds((__attribute__((address_space(1))) void*)(g),
                                   (__attribute__((address_space(3))) void*)(l),
                                   16, 0, 0);
}

// fast gelu: Abramowitz-Stegun 7.1.26 erf (|eps|<=1.5e-7, far below f16 output
// precision). ~12 VALU ops vs libm erff's ~35.
__device__ __forceinline__ float fast_gelu(float t) {
  const float z  = t * 0.70710678118654752f;
  const float az = fabsf(z);
  const float u  = __builtin_amdgcn_rcpf(1.0f + 0.3275911f * az);
  const float p  = u*(0.254829592f + u*(-0.284496736f + u*(1.421413741f +
                   u*(-1.453152027f + u*1.061405429f))));
  const float e  = 1.0f - p * __builtin_amdgcn_exp2f(-az*az*1.44269504089f);
  const float er = (z < 0.0f) ? -e : e;
  return 0.5f * t * (1.0f + er);
}

// ---- fused: weight transpose (blocks 0..8191) + LayerNorm1 (blocks 8192..16383)
// ---- + inv-perm scatter (block 16384) ----
__global__ __launch_bounds__(256) void wt_ln_kernel(
    const float* __restrict__ Wqkv, const float* __restrict__ Wproj,
    const float* __restrict__ Wff1, const float* __restrict__ Wff2,
    f16* __restrict__ WqkvT, f16* __restrict__ WprojT,
    f16* __restrict__ Wff1T, f16* __restrict__ Wff2T,
    const float* __restrict__ x, const float* __restrict__ gam,
    const float* __restrict__ bet, f16* __restrict__ lnout,
    const int* __restrict__ perm, int* __restrict__ inv) {
  const int tid = threadIdx.x;
  if (blockIdx.x >= 16384) {
    // inv[perm[t]] = t : key with perm value j lives at original row inv[j]
    #pragma unroll
    for (int i = tid; i < Tt; i += 256) inv[perm[i]] = i;
    return;
  }
  if (blockIdx.x < 8192) {
    __shared__ float tile[32][33];
    int idx = blockIdx.x;
    const float* W; f16* WT; int K, N, n0, k0;
    if (idx < 3072)      { W = Wqkv;  WT = WqkvT;  K = Cc;  N = 3*Cc; n0 = (idx % 96)*32; k0 = (idx / 96)*32; }
    else if (idx < 4096) { idx -= 3072; W = Wproj; WT = WprojT; K = Cc;  N = Cc;  n0 = (idx % 32)*32; k0 = (idx / 32)*32; }
    else if (idx < 6144) { idx -= 4096; W = Wff1;  WT = Wff1T;  K = Cc;  N = FFf; n0 = (idx % 64)*32; k0 = (idx / 64)*32; }
    else                 { idx -= 6144; W = Wff2;  WT = Wff2T;  K = FFf; N = Cc;  n0 = (idx % 32)*32; k0 = (idx / 32)*32; }
    const int tx = tid & 31, ty = tid >> 5;
    #pragma unroll
    for (int i = 0; i < 4; i++)
      tile[ty + 8*i][tx] = W[(size_t)(k0 + ty + 8*i) * N + n0 + tx];
    __syncthreads();
    #pragma unroll
    for (int i = 0; i < 4; i++)
      WT[(size_t)(n0 + ty + 8*i) * K + k0 + tx] = (f16)tile[tx][ty + 8*i];
  } else {
    const int row = blockIdx.x - 8192;
    const float4 v = ((const float4*)(x + (size_t)row * Cc))[tid];
    float s  = v.x + v.y + v.z + v.w;
    float ss = v.x*v.x + v.y*v.y + v.z*v.z + v.w*v.w;
    #pragma unroll
    for (int o = 32; o >= 1; o >>= 1) { s += __shfl_xor(s, o); ss += __shfl_xor(ss, o); }
    __shared__ float ps[4], pss[4];
    if ((tid & 63) == 0) { ps[tid >> 6] = s; pss[tid >> 6] = ss; }
    __syncthreads();
    s  = ps[0] + ps[1] + ps[2] + ps[3];
    ss = pss[0] + pss[1] + pss[2] + pss[3];
    const float mu   = s * (1.0f / Cc);
    const float rstd = rsqrtf(ss * (1.0f / Cc) - mu * mu + 1e-5f);
    const float4 g4 = ((const float4*)gam)[tid];
    const float4 b4 = ((const float4*)bet)[tid];
    half4 o;
    o[0] = (f16)((v.x - mu) * rstd * g4.x + b4.x);
    o[1] = (f16)((v.y - mu) * rstd * g4.y + b4.y);
    o[2] = (f16)((v.z - mu) * rstd * g4.z + b4.z);
    o[3] = (f16)((v.w - mu) * rstd * g4.w + b4.w);
    ((half4*)(lnout + (size_t)row * Cc))[tid] = o;
  }
}

// ---------------- LayerNorm: fp32 in -> f16 out ----------------
__global__ __launch_bounds__(256) void ln_kernel(const float* __restrict__ x,
                                                 const float* __restrict__ gam,
                                                 const float* __restrict__ bet,
                                                 f16* __restrict__ out) {
  const int row = blockIdx.x;
  const int tid = threadIdx.x;
  const float4 v = ((const float4*)(x + (size_t)row * Cc))[tid];
  float s  = v.x + v.y + v.z + v.w;
  float ss = v.x*v.x + v.y*v.y + v.z*v.z + v.w*v.w;
  #pragma unroll
  for (int o = 32; o >= 1; o >>= 1) { s += __shfl_xor(s, o); ss += __shfl_xor(ss, o); }
  __shared__ float ps[4], pss[4];
  if ((tid & 63) == 0) { ps[tid >> 6] = s; pss[tid >> 6] = ss; }
  __syncthreads();
  s  = ps[0] + ps[1] + ps[2] + ps[3];
  ss = pss[0] + pss[1] + pss[2] + pss[3];
  const float mu   = s * (1.0f / Cc);
  const float rstd = rsqrtf(ss * (1.0f / Cc) - mu * mu + 1e-5f);
  const float4 g4 = ((const float4*)gam)[tid];
  const float4 b4 = ((const float4*)bet)[tid];
  half4 o;
  o[0] = (f16)((v.x - mu) * rstd * g4.x + b4.x);
  o[1] = (f16)((v.y - mu) * rstd * g4.y + b4.y);
  o[2] = (f16)((v.z - mu) * rstd * g4.z + b4.z);
  o[3] = (f16)((v.w - mu) * rstd * g4.w + b4.w);
  ((half4*)(out + (size_t)row * Cc))[tid] = o;
}

// -------- shared epilogue helper (32x32 C layout: col=lane&31, row=(reg&3)+8*(reg>>2)+4*khalf) --------
template <int MODE>
__device__ __forceinline__ void gemm_epilogue_tile(
    const floatx16& a, int rowBase, int col, int khalf,
    const float* __restrict__ resid, const float* __restrict__ bias,
    float* __restrict__ outF, f16* __restrict__ outH,
    f16* __restrict__ outQ, f16* __restrict__ outK, f16* __restrict__ outV) {
  if (MODE == 0) {
    const int s = col >> 10;
    const int hh = (col >> 6) & 15;
    const int d = col & 63;
    #pragma unroll
    for (int g = 0; g < 4; g++) {
      const int row0 = rowBase + 4*khalf + 8*g;
      const int bI = row0 >> 11;
      const int t0 = row0 & 2047;
      if (s == 2) {
        const size_t addr = (((size_t)(bI*Hh + hh)) * Dd + d) * Tt +
                            (t0 & ~63) + ((t0 >> 2) & 3)*16 + ((t0 >> 4) & 3)*4;
        half4 o;
        #pragma unroll
        for (int r = 0; r < 4; r++) o[r] = (f16)a[g*4 + r];
        *(half4*)&outV[addr] = o;
      } else {
        f16* dst = (s == 0) ? outQ : outK;
        const float sc = (s == 0) ? 0.18033688f : 1.0f;  // (1/8)*log2(e) folded into q
        #pragma unroll
        for (int r = 0; r < 4; r++)
          dst[(((size_t)(bI*Hh + hh)) * Tt + t0 + r) * Dd + d] = (f16)(a[g*4 + r] * sc);
      }
    }
  } else {
    #pragma unroll
    for (int g = 0; g < 4; g++) {
      #pragma unroll
      for (int r = 0; r < 4; r++) {
        const int row = rowBase + 4*khalf + 8*g + r;
        const float vv = a[g*4 + r];
        if (MODE == 1) {
          const size_t ad = (size_t)row * Cc + col;
          outF[ad] = vv + resid[ad] + bias[col];
        } else if (MODE == 2) {
          outH[(size_t)row * FFf + col] = (f16)fast_gelu(vv + bias[col]);
        } else {
          const size_t ad = (size_t)row * Cc + col;
          outF[ad] = vv + bias[col] + resid[ad];
        }
      }
    }
  }
}

// ------------- GEMM 128x128: 32x32x16 MFMA, BK=64, swizzled staging -------------
// Proven inner loop (R3/R6/R8). L2-blocked swizzle: each XCD (fid&7) owns a
// contiguous 8-bm slab; bn inner in groups of 8. MODE 0 + bn>=8: A gathered via inv[].
// R9: modes 1/3 (N=1024 -> only 512 blocks = 2 blocks/CU = 8 waves/CU, the
// latency-starved regime R8's attn dbuf fixed) get a double-buffered K-loop:
// prefetch t+1 into alt 32KB buffer, compute t, ONE __syncthreads per step (its
// implicit vmcnt drain lands the prefetch after it had the 16-MFMA phase in
// flight). LDS 64KB -> 2 blocks/CU cap = what they already get, so dbuf is free.
// Modes 0/2 stay single-buffered (4 blocks/CU; m99/m100-null regime).
template <int MODE>
__global__ __launch_bounds__(256, 4) void gemm_kernel(
    const f16* __restrict__ A, const f16* __restrict__ Bt, const int Kdim,
    const float* __restrict__ resid, const float* __restrict__ bias,
    float* __restrict__ outF, f16* __restrict__ outH,
    f16* __restrict__ outQ, f16* __restrict__ outK, f16* __restrict__ outV,
    const int* __restrict__ inv) {
  constexpr int NB = (MODE == 1 || MODE == 3) ? 2 : 1;
  __shared__ f16 As[NB][128 * 64];
  __shared__ f16 Bs[NB][128 * 64];
  const int tid = threadIdx.x;
  const int lane = tid & 63;
  const int w = tid >> 6;
  const int wr = w >> 1, wc = w & 1;

  const int fid = blockIdx.y * gridDim.x + blockIdx.x;
  const int xcd = fid & 7;
  const int s = fid >> 3;
  const int r = s & 63;
  const int bm = xcd * 8 + (r >> 3);
  const int bn = (s >> 6) * 8 + (r & 7);

  floatx16 acc[2][2] = {};

  const int srow = lane >> 3;
  const int scol = ((lane & 7) ^ srow) * 8;
  size_t aRow[4];
  {
    const int r0 = bm*128 + w*32 + srow;
    if (MODE == 0 && bn >= 8) {
      const int bI = r0 >> 11;
      const int t0 = r0 & 2047;
      #pragma unroll
      for (int c = 0; c < 4; c++)
        aRow[c] = (size_t)(bI*Tt + inv[t0 + c*8]) * Kdim + scol;
    } else {
      #pragma unroll
      for (int c = 0; c < 4; c++)
        aRow[c] = (size_t)(r0 + c*8) * Kdim + scol;
    }
  }
  const size_t bBase = (size_t)(bn*128 + w*32 + srow) * Kdim + scol;

  const int m0 = wr*64 + (lane & 31);
  const int n0 = wc*64 + (lane & 31);
  const int khalf = lane >> 5;
  const int mx = (lane & 7);

  auto stage = [&](int buf, int ks) {
    #pragma unroll
    for (int c = 0; c < 4; c++) {
      g2l16(A  + aRow[c] + ks, &As[buf][(w*32 + c*8) * 64]);
      g2l16(Bt + bBase + (size_t)(c*8)*Kdim + ks, &Bs[buf][(w*32 + c*8) * 64]);
    }
  };
  auto compute = [&](int buf) {
    #pragma unroll
    for (int kk = 0; kk < 4; kk++) {
      const int kg = kk*2 + khalf;
      half8 aF[2], bF[2];
      aF[0] = *(const half8*)&As[buf][(m0     ) * 64 + ((kg ^ mx) * 8)];
      aF[1] = *(const half8*)&As[buf][(m0 + 32) * 64 + ((kg ^ mx) * 8)];
      bF[0] = *(const half8*)&Bs[buf][(n0     ) * 64 + ((kg ^ mx) * 8)];
      bF[1] = *(const half8*)&Bs[buf][(n0 + 32) * 64 + ((kg ^ mx) * 8)];
      acc[0][0] = MFMA32(aF[0], bF[0], acc[0][0]);
      acc[0][1] = MFMA32(aF[0], bF[1], acc[0][1]);
      acc[1][0] = MFMA32(aF[1], bF[0], acc[1][0]);
      acc[1][1] = MFMA32(aF[1], bF[1], acc[1][1]);
    }
  };

  if constexpr (NB == 2) {
    stage(0, 0);
    __syncthreads();
    const int NT = Kdim >> 6;
    for (int t = 0; t < NT; ++t) {
      const int cur = t & 1;
      if (t + 1 < NT) stage(cur ^ 1, (t + 1) << 6);
      compute(cur);
      __syncthreads();
    }
  } else {
    for (int ks = 0; ks < Kdim; ks += 64) {
      __syncthreads();
      stage(0, ks);
      __syncthreads();
      compute(0);
    }
  }

  #pragma unroll
  for (int mi = 0; mi < 2; mi++)
    #pragma unroll
    for (int ni = 0; ni < 2; ni++)
      gemm_epilogue_tile<MODE>(acc[mi][ni], bm*128 + wr*64 + mi*32,
                               bn*128 + wc*64 + ni*32 + (lane & 31), khalf,
                               resid, bias, outF, outH, outQ, outK, outV);
}

// ---------------- flash attention: 8-wave blocks, double-buffered K/V staging ----------------
// Keys/values perm-sorted -> causal mask in sorted key index j: masked iff j > qrow.
// Each block = 512 threads (8 waves x 16 q-rows) processing TWO q-tiles (y, 15-y):
// exactly 36 key-block iterations per block, uniform under any scheduling.
// R8: issue-early double-buffer. R9: + s_setprio(1) around MFMA clusters (T5 —
// dbuf gives waves phase-role diversity; m191 measured +4-7% on attn).
__global__ __launch_bounds__(512, 4) void attn_kernel(
    const f16* __restrict__ Q, const f16* __restrict__ Kg,
    const f16* __restrict__ Vtp, f16* __restrict__ Y) {
  __shared__ f16 Ks[2][64 * 64];
  __shared__ f16 Vs[2][64 * 64];

  const int tid = threadIdx.x;
  const int lane = tid & 63;
  const int w = tid >> 6;
  const int low = lane & 15;
  const int quad = lane >> 4;
  const int bh = blockIdx.x;
  const int y = blockIdx.y;
  const int b = bh >> 4, h = bh & 15;

  const half4 ones4 = {(f16)1.f, (f16)1.f, (f16)1.f, (f16)1.f};
  const int gd = ((lane & 7) ^ (lane >> 3)) * 8;
  const int krow = lane >> 3;
  const size_t kgB = (size_t)bh * Tt * Dd + (size_t)(w*8 + krow) * Dd + gd;
  const size_t vgB = (size_t)bh * Dd * Tt + (size_t)(w*8 + krow) * Tt + gd;

  for (int pi = 0; pi < 2; pi++) {
    const int tile = (pi == 0) ? y : 15 - y;
    const int q0 = tile * 128;

    half8 qF[2];
    {
      const size_t base = ((size_t)bh * Tt + q0 + w*16) * Dd;
      #pragma unroll
      for (int kc = 0; kc < 2; kc++)
        qF[kc] = *(const half8*)(Q + base + (size_t)low * Dd + kc*32 + quad*8);
    }

    floatx4 O[4] = {};
    floatx4 Ol = {};
    const int nkb = (q0 >> 6) + 2;

    // prologue: stage kt=0 into buffer 0 (prev pi's trailing barrier guards reuse)
    g2l16(Kg  + kgB, &Ks[0][w * 512]);
    g2l16(Vtp + vgB, &Vs[0][w * 512]);
    __syncthreads();

    for (int kt = 0; kt < nkb; kt++) {
      const int cur = kt & 1;
      const int kbase = kt * 64;
      if (kt + 1 < nkb) {
        g2l16(Kg  + kgB + (size_t)(kbase + 64) * Dd, &Ks[cur ^ 1][w * 512]);
        g2l16(Vtp + vgB + (kbase + 64),              &Vs[cur ^ 1][w * 512]);
      }
      const f16* Kc = &Ks[cur][0];
      const f16* Vc = &Vs[cur][0];

      floatx4 S[4] = {};
      __builtin_amdgcn_s_setprio(1);
      #pragma unroll
      for (int kc = 0; kc < 2; kc++) {
        #pragma unroll
        for (int ki = 0; ki < 4; ki++) {
          const int key = ki*16 + low;
          const half8 kf = *(const half8*)&Kc[key * 64 + (((kc*4 + quad) ^ (lane & 7)) * 8)];
          S[ki] = MFMA16(kf, qF[kc], S[ki]);
        }
      }
      __builtin_amdgcn_s_setprio(0);

      half4 pF[4];
      const bool needmask = (kbase + 63 > q0 + w*16);  // wave-uniform
      if (needmask) {
        const int qrow = q0 + w*16 + low;
        #pragma unroll
        for (int ki = 0; ki < 4; ki++) {
          const floatx4 sv = S[ki];
          const int kj = kbase + ki*16 + quad*4;
          const float p0 = (kj + 0 > qrow) ? 0.f : __builtin_amdgcn_exp2f(sv[0]);
          const float p1 = (kj + 1 > qrow) ? 0.f : __builtin_amdgcn_exp2f(sv[1]);
          const float p2 = (kj + 2 > qrow) ? 0.f : __builtin_amdgcn_exp2f(sv[2]);
          const float p3 = (kj + 3 > qrow) ? 0.f : __builtin_amdgcn_exp2f(sv[3]);
          const half2 lo = __builtin_bit_cast(half2, __builtin_amdgcn_cvt_pkrtz(p0, p1));
          const half2 hi = __builtin_bit_cast(half2, __builtin_amdgcn_cvt_pkrtz(p2, p3));
          pF[ki] = __builtin_shufflevector(lo, hi, 0, 1, 2, 3);
        }
      } else {
        #pragma unroll
        for (int ki = 0; ki < 4; ki++) {
          const floatx4 sv = S[ki];
          const float p0 = __builtin_amdgcn_exp2f(sv[0]);
          const float p1 = __builtin_amdgcn_exp2f(sv[1]);
          const float p2 = __builtin_amdgcn_exp2f(sv[2]);
          const float p3 = __builtin_amdgcn_exp2f(sv[3]);
          const half2 lo = __builtin_bit_cast(half2, __builtin_amdgcn_cvt_pkrtz(p0, p1));
          const half2 hi = __builtin_bit_cast(half2, __builtin_amdgcn_cvt_pkrtz(p2, p3));
          pF[ki] = __builtin_shufflevector(lo, hi, 0, 1, 2, 3);
        }
      }

      __builtin_amdgcn_s_setprio(1);
      #pragma unroll
      for (int ki2 = 0; ki2 < 2; ki2++) {
        Ol = MFMA16K16(ones4, pF[2*ki2 + 0], Ol);
        Ol = MFMA16K16(ones4, pF[2*ki2 + 1], Ol);
        #pragma unroll
        for (int ni = 0; ni < 4; ni++) {
          const int d = ni*16 + low;
          const half8 v8 = *(const half8*)&Vc[d * 64 + (((quad*2 + ki2) ^ (lane & 7)) * 8)];
          const half4 vfA = __builtin_shufflevector(v8, v8, 0, 1, 2, 3);
          const half4 vfB = __builtin_shufflevector(v8, v8, 4, 5, 6, 7);
          O[ni] = MFMA16K16(vfA, pF[2*ki2 + 0], O[ni]);
          O[ni] = MFMA16K16(vfB, pF[2*ki2 + 1], O[ni]);
        }
      }
      __builtin_amdgcn_s_setprio(0);
      __syncthreads();
    }

    {
      const float linv = 1.0f / Ol[0];
      const int trow = q0 + w*16 + low;
      #pragma unroll
      for (int ni = 0; ni < 4; ni++) {
        half4 o;
        #pragma unroll
        for (int rr = 0; rr < 4; rr++) o[rr] = (f16)(O[ni][rr] * linv);
        *(half4*)&Y[((size_t)(b * Tt + trow)) * Cc + h*64 + ni*16 + quad*4] = o;
      }
    }
  }
}

extern "C" void kernel_launch(void* const* d_in, const int* in_sizes, int n_in,
                              void* d_out, int out_size, void* d_ws, size_t ws_size,
                              hipStream_t stream) {
  const float* x     = (const float*)d_in[0];
  const int*   perm  = (const int*)d_in[1];
  const float* Wqkv  = (const float*)d_in[2];
  const float* Wproj = (const float*)d_in[3];
  const float* bproj = (const float*)d_in[4];
  const float* ln1g  = (const float*)d_in[5];
  const float* ln1b  = (const float*)d_in[6];
  const float* ln2g  = (const float*)d_in[7];
  const float* ln2b  = (const float*)d_in[8];
  const float* Wff1  = (const float*)d_in[9];
  const float* bff1  = (const float*)d_in[10];
  const float* Wff2  = (const float*)d_in[11];
  const float* bff2  = (const float*)d_in[12];
  float* out = (float*)d_out;

  char* ws = (char*)d_ws;
  size_t off = 0;
  auto alloc = [&](size_t bytes) -> void* {
    void* p = ws + off;
    off += (bytes + 255) & ~(size_t)255;
    return p;
  };
  f16*   h1     = (f16*)alloc((size_t)Mrows * Cc * 2);
  f16*   qb     = (f16*)alloc((size_t)Mrows * Cc * 2);
  f16*   kb     = (f16*)alloc((size_t)Mrows * Cc * 2);
  f16*   vtp    = (f16*)alloc((size_t)Mrows * Cc * 2);
  f16*   yb     = (f16*)alloc((size_t)Mrows * Cc * 2);
  float* xa     = (float*)alloc((size_t)Mrows * Cc * 4);
  f16*   h2     = (f16*)alloc((size_t)Mrows * Cc * 2);
  f16*   gb     = (f16*)alloc((size_t)Mrows * FFf * 2);
  f16*   WqkvT  = (f16*)alloc((size_t)3 * Cc * Cc * 2);
  f16*   WprojT = (f16*)alloc((size_t)Cc * Cc * 2);
  f16*   Wff1T  = (f16*)alloc((size_t)FFf * Cc * 2);
  f16*   Wff2T  = (f16*)alloc((size_t)Cc * FFf * 2);
  int*   inv    = (int*)alloc((size_t)Tt * 4);

  wt_ln_kernel<<<16385, 256, 0, stream>>>(Wqkv, Wproj, Wff1, Wff2,
                                          WqkvT, WprojT, Wff1T, Wff2T,
                                          x, ln1g, ln1b, h1, perm, inv);

  gemm_kernel<0><<<dim3(3*Cc/128, Mrows/128), 256, 0, stream>>>(
      h1, WqkvT, Cc, nullptr, nullptr, nullptr, nullptr, qb, kb, vtp, inv);

  attn_kernel<<<dim3(Bb*Hh, Tt/256), 512, 0, stream>>>(qb, kb, vtp, yb);

  gemm_kernel<1><<<dim3(Cc/128, Mrows/128), 256, 0, stream>>>(
      yb, WprojT, Cc, x, bproj, xa, nullptr, nullptr, nullptr, nullptr, nullptr);

  ln_kernel<<<Mrows, 256, 0, stream>>>(xa, ln2g, ln2b, h2);

  gemm_kernel<2><<<dim3(FFf/128, Mrows/128), 256, 0, stream>>>(
      h2, Wff1T, Cc, nullptr, bff1, nullptr, gb, nullptr, nullptr, nullptr, nullptr);

  gemm_kernel<3><<<dim3(Cc/128, Mrows/128), 256, 0, stream>>>(
      gb, Wff2T, FFf, xa, bff2, out, nullptr, nullptr, nullptr, nullptr, nullptr);
}